// Round 16
// baseline (254.971 us; speedup 1.0000x reference)
//
#include <hip/hip_runtime.h>
#include <hip/hip_bf16.h>

#define NTOK 49
#define NP 64
#define CDIM 256
#define NH 8
#define SCALE 0.17677669529663687f

// per-batch ws images, TILED (plain in global):
//   Q: 8 tiles [64 rows][32 cols] bf16 (4KB/head)  at +0
//   K: same                                        at +32768
//   Vt: 8 tiles [32 feat][64 tok] bf16             at +65536
#define IMG_STRIDE 98304

using f32x4  = __attribute__((ext_vector_type(4))) float;
using bf16x8 = __attribute__((ext_vector_type(8))) short;

__device__ __forceinline__ unsigned f2bf_u(float f) {
  union { float f; unsigned u; } c; c.f = f;
  return (c.u + 0x7fffu + ((c.u >> 16) & 1u)) >> 16;   // RNE
}
__device__ __forceinline__ unsigned pk2(float a, float b) {
  return f2bf_u(a) | (f2bf_u(b) << 16);
}

// ---- LDS byte-offset helpers (XOR swizzles preserve 16B alignment) ----
__device__ __forceinline__ int sx_b(int row, int col) {   // bf16 [64][256] x-stage / O image
  return (row * 512 + col * 2) ^ ((row & 7) << 4);
}
__device__ __forceinline__ int sp_b(int w, int row, int key) { // bf16 per-wave [16][64] P
  return w * 2048 + ((row * 128 + key * 2) ^ ((row & 7) << 4));
}
// wave-private 2KB patch: 32 logical rows x 64B, XOR bits 5-6 by (row>>2)&3
__device__ __forceinline__ int pt_b(int prow, int byte_in_row) {
  return (prow * 64 + byte_in_row) ^ (((prow >> 2) & 3) << 5);
}
// fused3 fallback helpers
__device__ __forceinline__ int rm2_b(int row, int col) {  // [32][32] bf16 2KB
  return (row * 64 + col * 2) ^ ((row & 7) << 4);
}
__device__ __forceinline__ int vt2_b(int feat, int tok) { // [32][32] bf16 2KB
  return (feat * 64 + tok * 2) ^ ((feat & 7) << 4);
}
__device__ __forceinline__ int p2_b(int q, int tok) {     // [16][64] bf16 2KB
  return (q * 128 + tok * 2) ^ ((q & 7) << 4);
}

// ---------------- prep: bf16 weights (scale folded into Wq), TRANSPOSED bias table
// bias_att layout: [h][key_col][query_row] f32
__global__ void prep_kernel(const float* __restrict__ qkv_w, const float* __restrict__ qkv_b,
                            const float* __restrict__ proj_w,
                            const float* __restrict__ rpb, const int* __restrict__ rel,
                            short* __restrict__ wqkv, short* __restrict__ wp,
                            float* __restrict__ bias_s, float* __restrict__ bias_att) {
  int i = blockIdx.x * 256 + threadIdx.x;
  if (i < 768 * 256) {
    int j = i >> 8;
    float v = qkv_w[i] * (j < 256 ? SCALE : 1.0f);
    wqkv[i] = (short)f2bf_u(v);
    return;
  }
  i -= 768 * 256;
  if (i < 256 * 256) { wp[i] = (short)f2bf_u(proj_w[i]); return; }
  i -= 256 * 256;
  if (i < 768) { bias_s[i] = qkv_b[i] * (i < 256 ? SCALE : 1.0f); return; }
  i -= 768;
  if (i < NH * NP * NP) {
    int h = i >> 12, rem = i & 4095, c = rem >> 6, r = rem & 63;
    float v;
    if (c >= NTOK)      v = -1e30f;      // mask padded key columns
    else if (r >= NTOK) v = 0.0f;        // padded query rows
    else                v = rpb[rel[r * NTOK + c] * NH + h];
    bias_att[i] = v;
  }
}

// 64x32(x256) per-wave GEMM, k-outer (fallback + consumer proj use this)
__device__ __forceinline__ void gemm32c(const char* sxc, const short* __restrict__ wg,
                                        const float* __restrict__ bias,
                                        f32x4 acc[4][2], int col0, int lr, int lg) {
  const short* wr0 = wg + (col0 + lr) * CDIM + lg * 8;
  const short* wr1 = wg + (col0 + 16 + lr) * CDIM + lg * 8;
  const float bv0 = bias[col0 + lr];
  const float bv1 = bias[col0 + 16 + lr];
  #pragma unroll
  for (int rt = 0; rt < 4; ++rt) {
    #pragma unroll
    for (int r = 0; r < 4; ++r) { acc[rt][0][r] = bv0; acc[rt][1][r] = bv1; }
  }
  #pragma unroll
  for (int k = 0; k < 8; ++k) {
    const bf16x8 b0 = *(const bf16x8*)(wr0 + k * 32);
    const bf16x8 b1 = *(const bf16x8*)(wr1 + k * 32);
    #pragma unroll
    for (int rt = 0; rt < 4; ++rt) {
      const bf16x8 af = *(const bf16x8*)(sxc + sx_b(rt * 16 + lr, k * 32 + lg * 8));
      acc[rt][0] = __builtin_amdgcn_mfma_f32_16x16x32_bf16(af, b0, acc[rt][0], 0, 0, 0);
      acc[rt][1] = __builtin_amdgcn_mfma_f32_16x16x32_bf16(af, b1, acc[rt][1], 0, 0, 0);
    }
  }
}

// weight preload: all 16 fragments + bias into registers (batched loads, 1 latency window)
__device__ __forceinline__ void wpre(const short* __restrict__ wg,
                                     const float* __restrict__ bias,
                                     bf16x8 bfr[2][8], float bv[2],
                                     int col0, int lr, int lg) {
  const short* wr0 = wg + (col0 + lr) * CDIM + lg * 8;
  const short* wr1 = wg + (col0 + 16 + lr) * CDIM + lg * 8;
  #pragma unroll
  for (int k = 0; k < 8; ++k) {
    bfr[0][k] = *(const bf16x8*)(wr0 + k * 32);
    bfr[1][k] = *(const bf16x8*)(wr1 + k * 32);
  }
  bv[0] = bias[col0 + lr];
  bv[1] = bias[col0 + 16 + lr];
}

// MFMA loop consuming preloaded weights; A from swizzled LDS
__device__ __forceinline__ void gemm32m(const char* sxc, const bf16x8 bfr[2][8],
                                        const float bv[2], f32x4 acc[4][2],
                                        int lr, int lg) {
  #pragma unroll
  for (int rt = 0; rt < 4; ++rt) {
    #pragma unroll
    for (int r = 0; r < 4; ++r) { acc[rt][0][r] = bv[0]; acc[rt][1][r] = bv[1]; }
  }
  #pragma unroll
  for (int k = 0; k < 8; ++k) {
    #pragma unroll
    for (int rt = 0; rt < 4; ++rt) {
      const bf16x8 af = *(const bf16x8*)(sxc + sx_b(rt * 16 + lr, k * 32 + lg * 8));
      acc[rt][0] = __builtin_amdgcn_mfma_f32_16x16x32_bf16(af, bfr[0][k], acc[rt][0], 0, 0, 0);
      acc[rt][1] = __builtin_amdgcn_mfma_f32_16x16x32_bf16(af, bfr[1][k], acc[rt][1], 0, 0, 0);
    }
  }
}

// stage one batch of x (f32->bf16, rows >=49 zeroed) into sx; 512 threads
__device__ __forceinline__ void stage_x(char* sxc, const float* __restrict__ xg, int tid) {
  #pragma unroll
  for (int it = 0; it < 8; ++it) {
    const int i = tid + it * 512;
    const int row = i >> 6, c4 = i & 63;
    uint2 pkv = make_uint2(0u, 0u);
    if (row < NTOK) {
      const float4 v = *(const float4*)(xg + row * CDIM + c4 * 4);
      pkv.x = pk2(v.x, v.y); pkv.y = pk2(v.z, v.w);
    }
    *(uint2*)(sxc + sx_b(row, c4 * 4)) = pkv;
  }
}

// acc (64 rows x 32 cols) -> row-major tile [64][32] bf16 via 2KB wave patch.
__device__ __forceinline__ void store_rm_tile(char* __restrict__ gt, const f32x4 acc[4][2],
                                              char* pt, int lane, int lr, int lg) {
  #pragma unroll 1
  for (int R = 0; R < 2; ++R) {
    #pragma unroll
    for (int rh = 0; rh < 2; ++rh)
      #pragma unroll
      for (int ct = 0; ct < 2; ++ct)
        #pragma unroll
        for (int r = 0; r < 4; ++r) {
          const int prow = rh * 16 + lg * 4 + r;
          *(short*)(pt + pt_b(prow, (ct * 16 + lr) * 2)) =
              (short)f2bf_u(acc[2 * R + rh][ct][r]);
        }
    #pragma unroll
    for (int i = 0; i < 2; ++i) {
      const int c = i * 64 + lane;
      const int prow = c >> 2, seg = c & 3;
      const float4 v = *(const float4*)(pt + pt_b(prow, seg * 16));
      *(float4*)(gt + (R * 32 + prow) * 64 + seg * 16) = v;
    }
  }
}

// acc (rows=tok, cols=feat) -> Vt tile [32 feat][64 tok] bf16 via patch.
__device__ __forceinline__ void store_vt_tile(char* __restrict__ gt, const f32x4 acc[4][2],
                                              char* pt, int lane, int lr, int lg) {
  #pragma unroll 1
  for (int R = 0; R < 2; ++R) {
    #pragma unroll
    for (int rh = 0; rh < 2; ++rh)
      #pragma unroll
      for (int ct = 0; ct < 2; ++ct) {
        const int f = ct * 16 + lr;
        const int tok = rh * 16 + lg * 4;
        uint2 pkv = make_uint2(pk2(acc[2 * R + rh][ct][0], acc[2 * R + rh][ct][1]),
                               pk2(acc[2 * R + rh][ct][2], acc[2 * R + rh][ct][3]));
        *(uint2*)(pt + pt_b(f, tok * 2)) = pkv;
      }
    #pragma unroll
    for (int i = 0; i < 2; ++i) {
      const int c = i * 64 + lane;
      const int f = c >> 2, seg = c & 3;
      const float4 v = *(const float4*)(pt + pt_b(f, seg * 16));
      *(float4*)(gt + f * 128 + R * 64 + seg * 16) = v;
    }
  }
}

// ================= producer (R8 + weight-preload; Q-weights hoisted above barrier) ========
__global__ __launch_bounds__(512, 2)
void qkv_kernel(const float* __restrict__ x1, const float* __restrict__ x2,
                const short* __restrict__ wqkv, const float* __restrict__ bias_s,
                char* __restrict__ img) {
  extern __shared__ char ldsq[];
  char* sx1   = ldsq;                 // 32 KB x1
  char* sx2   = ldsq + 32768;         // 32 KB x2
  char* patch = ldsq + 65536;         // 8 x 2 KB wave patches

  const int tid = threadIdx.x;
  const int w = tid >> 6, lane = tid & 63;
  const int lr = lane & 15, lg = lane >> 4;
  const int b = blockIdx.x;
  char* wsb = img + (size_t)b * IMG_STRIDE;
  char* pt = patch + w * 2048;
  const int ht = w;                    // wave = head slice

  stage_x(sx1, x1 + (size_t)b * NTOK * CDIM, tid);
  stage_x(sx2, x2 + (size_t)b * NTOK * CDIM, tid);

  // Q weight preload BEFORE the barrier: overlaps with staging drain
  bf16x8 bfr[2][8];
  float bv[2];
  wpre(wqkv, bias_s, bfr, bv, ht * 32, lr, lg);
  __syncthreads();

  f32x4 acc[4][2];

  gemm32m(sx1, bfr, bv, acc, lr, lg);
  store_rm_tile(wsb + ht * 4096, acc, pt, lane, lr, lg);

  wpre(wqkv + 512 * CDIM, bias_s + 512, bfr, bv, ht * 32, lr, lg);
  gemm32m(sx2, bfr, bv, acc, lr, lg);
  store_vt_tile(wsb + 65536 + ht * 4096, acc, pt, lane, lr, lg);

  wpre(wqkv + 256 * CDIM, bias_s + 256, bfr, bv, ht * 32, lr, lg);
  gemm32m(sx2, bfr, bv, acc, lr, lg);
  store_rm_tile(wsb + 32768 + ht * 4096, acc, pt, lane, lr, lg);
}

// ================= consumer (R11/R15 verbatim -- ~75 us) =================
__global__ __launch_bounds__(256, 2)
void attnproj_kernel(const char* __restrict__ img, const short* __restrict__ wp,
                     const float* __restrict__ proj_b, const float* __restrict__ bias_att,
                     float* __restrict__ out) {
  extern __shared__ char ldsc[];
  char* soc = ldsc;            // 32 KB O image (sx_b LDS layout)
  char* spc = ldsc + 32768;    // 8 KB P (2 KB per wave)

  const int tid = threadIdx.x;
  const int w = tid >> 6, lane = tid & 63;
  const int lr = lane & 15, lg = lane >> 4;
  const int b = blockIdx.x;
  const char* qimg = img + (size_t)b * IMG_STRIDE;
  const char* kimg = qimg + 32768;
  const char* vimg = qimg + 65536;

  #pragma unroll 1
  for (int hh = 0; hh < 2; ++hh) {
    const int h = w * 2 + hh;
    bf16x8 kb[4];
    #pragma unroll
    for (int ct = 0; ct < 4; ++ct)
      kb[ct] = *(const bf16x8*)(kimg + h * 4096 + (ct * 16 + lr) * 64 + lg * 16);
    bf16x8 vb[2][2];
    #pragma unroll
    for (int kk = 0; kk < 2; ++kk)
      #pragma unroll
      for (int jt = 0; jt < 2; ++jt)
        vb[kk][jt] = *(const bf16x8*)(vimg + h * 4096 + (jt * 16 + lr) * 128 + kk * 64 + lg * 16);
    const float* bht = bias_att + h * NP * NP;   // [key][query]

    #pragma unroll 2
    for (int qt = 0; qt < 4; ++qt) {
      const bf16x8 qa = *(const bf16x8*)(qimg + h * 4096 + (qt * 16 + lr) * 64 + lg * 16);
      f32x4 s[4];
      #pragma unroll
      for (int ct = 0; ct < 4; ++ct) {
        const float4 sbv = *(const float4*)(bht + (ct * 16 + lr) * NP + qt * 16 + lg * 4);
        f32x4 sb; sb[0] = sbv.x; sb[1] = sbv.y; sb[2] = sbv.z; sb[3] = sbv.w;
        s[ct] = __builtin_amdgcn_mfma_f32_16x16x32_bf16(qa, kb[ct], sb, 0, 0, 0);
      }
      float mx[4], si[4];
      #pragma unroll
      for (int r = 0; r < 4; ++r) {
        float m = fmaxf(fmaxf(s[0][r], s[1][r]), fmaxf(s[2][r], s[3][r]));
        m = fmaxf(m, __shfl_xor(m, 1, 64));
        m = fmaxf(m, __shfl_xor(m, 2, 64));
        m = fmaxf(m, __shfl_xor(m, 4, 64));
        m = fmaxf(m, __shfl_xor(m, 8, 64));
        mx[r] = m;
      }
      #pragma unroll
      for (int ct = 0; ct < 4; ++ct)
        #pragma unroll
        for (int r = 0; r < 4; ++r)
          s[ct][r] = __expf(s[ct][r] - mx[r]);
      #pragma unroll
      for (int r = 0; r < 4; ++r) {
        float t = s[0][r] + s[1][r] + s[2][r] + s[3][r];
        t += __shfl_xor(t, 1, 64);
        t += __shfl_xor(t, 2, 64);
        t += __shfl_xor(t, 4, 64);
        t += __shfl_xor(t, 8, 64);
        si[r] = __builtin_amdgcn_rcpf(t);
      }
      #pragma unroll
      for (int ct = 0; ct < 4; ++ct)
        #pragma unroll
        for (int r = 0; r < 4; ++r)
          *(short*)(spc + sp_b(w, lg * 4 + r, ct * 16 + lr)) =
              (short)f2bf_u(s[ct][r] * si[r]);
      f32x4 oq[2];
      #pragma unroll
      for (int jt = 0; jt < 2; ++jt) { oq[jt][0] = 0; oq[jt][1] = 0; oq[jt][2] = 0; oq[jt][3] = 0; }
      #pragma unroll
      for (int kk = 0; kk < 2; ++kk) {
        const bf16x8 pa = *(const bf16x8*)(spc + sp_b(w, lr, kk * 32 + lg * 8));
        #pragma unroll
        for (int jt = 0; jt < 2; ++jt)
          oq[jt] = __builtin_amdgcn_mfma_f32_16x16x32_bf16(pa, vb[kk][jt], oq[jt], 0, 0, 0);
      }
      #pragma unroll
      for (int jt = 0; jt < 2; ++jt)
        #pragma unroll
        for (int r = 0; r < 4; ++r)
          *(short*)(soc + sx_b(qt * 16 + lg * 4 + r, h * 32 + jt * 16 + lr)) =
              (short)f2bf_u(oq[jt][r]);
    }
  }
  __syncthreads();   // O image complete

  float* og = out + (size_t)b * NTOK * CDIM;
  #pragma unroll 1
  for (int p = 0; p < 2; ++p) {
    const int c0 = w * 64 + p * 32;
    const short* wr0 = wp + (c0 + lr) * CDIM + lg * 8;
    const short* wr1 = wp + (c0 + 16 + lr) * CDIM + lg * 8;
    const float bv0 = proj_b[c0 + lr];
    const float bv1 = proj_b[c0 + 16 + lr];
    f32x4 acc[4][2];
    #pragma unroll
    for (int rt = 0; rt < 4; ++rt)
      #pragma unroll
      for (int r = 0; r < 4; ++r) { acc[rt][0][r] = bv0; acc[rt][1][r] = bv1; }
    #pragma unroll
    for (int k = 0; k < 8; ++k) {
      const bf16x8 b0 = *(const bf16x8*)(wr0 + k * 32);
      const bf16x8 b1 = *(const bf16x8*)(wr1 + k * 32);
      #pragma unroll
      for (int rt = 0; rt < 4; ++rt) {
        const bf16x8 af = *(const bf16x8*)(soc + sx_b(rt * 16 + lr, k * 32 + lg * 8));
        acc[rt][0] = __builtin_amdgcn_mfma_f32_16x16x32_bf16(af, b0, acc[rt][0], 0, 0, 0);
        acc[rt][1] = __builtin_amdgcn_mfma_f32_16x16x32_bf16(af, b1, acc[rt][1], 0, 0, 0);
      }
    }
    #pragma unroll
    for (int rt = 0; rt < 4; ++rt)
      #pragma unroll
      for (int r = 0; r < 4; ++r) {
        const int row = rt * 16 + lg * 4 + r;
        if (row < NTOK) {
          #pragma unroll
          for (int ct = 0; ct < 2; ++ct)
            og[row * CDIM + c0 + ct * 16 + lr] = acc[rt][ct][r];
        }
      }
  }
}

// ================= FUSED FALLBACK (R12 fused3, verified) =================
__global__ __launch_bounds__(512, 2)
void fused3(const float* __restrict__ x1, const float* __restrict__ x2,
            const short* __restrict__ wqkv, const float* __restrict__ bias_s,
            const short* __restrict__ wp, const float* __restrict__ proj_b,
            const float* __restrict__ bias_att, float* __restrict__ out) {
  extern __shared__ char lds[];
  char* sx1 = lds;
  char* sx2 = lds + 32768;
  char* pat = lds + 65536;

  const int tid = threadIdx.x;
  const int w = tid >> 6, lane = tid & 63;
  const int lr = lane & 15, lg = lane >> 4;
  const int b = blockIdx.x;
  char* pt = pat + w * 2048;

  stage_x(sx1, x1 + (size_t)b * NTOK * CDIM, tid);
  stage_x(sx2, x2 + (size_t)b * NTOK * CDIM, tid);
  __syncthreads();

  f32x4 acc[4][2];
  bf16x8 qa[4];
  gemm32c(sx1, wqkv, bias_s, acc, w * 32, lr, lg);
  #pragma unroll
  for (int R = 0; R < 2; ++R) {
    #pragma unroll
    for (int rh = 0; rh < 2; ++rh)
      #pragma unroll
      for (int ct = 0; ct < 2; ++ct)
        #pragma unroll
        for (int r = 0; r < 4; ++r)
          *(short*)(pt + rm2_b(rh * 16 + lg * 4 + r, ct * 16 + lr)) =
              (short)f2bf_u(acc[R * 2 + rh][ct][r]);
    qa[R * 2 + 0] = *(const bf16x8*)(pt + rm2_b(lr, lg * 8));
    qa[R * 2 + 1] = *(const bf16x8*)(pt + rm2_b(16 + lr, lg * 8));
  }
  bf16x8 kb[4];
  gemm32c(sx2, wqkv + 256 * CDIM, bias_s + 256, acc, w * 32, lr, lg);
  #pragma unroll
  for (int R = 0; R < 2; ++R) {
    #pragma unroll
    for (int rh = 0; rh < 2; ++rh)
      #pragma unroll
      for (int ct = 0; ct < 2; ++ct)
        #pragma unroll
        for (int r = 0; r < 4; ++r)
          *(short*)(pt + rm2_b(rh * 16 + lg * 4 + r, ct * 16 + lr)) =
              (short)f2bf_u(acc[R * 2 + rh][ct][r]);
    kb[R * 2 + 0] = *(const bf16x8*)(pt + rm2_b(lr, lg * 8));
    kb[R * 2 + 1] = *(const bf16x8*)(pt + rm2_b(16 + lr, lg * 8));
  }
  bf16x8 vb[2][2];
  gemm32c(sx2, wqkv + 512 * CDIM, bias_s + 512, acc, w * 32, lr, lg);
  #pragma unroll
  for (int K2 = 0; K2 < 2; ++K2) {
    #pragma unroll
    for (int rh = 0; rh < 2; ++rh)
      #pragma unroll
      for (int ct = 0; ct < 2; ++ct) {
        uint2 pkv = make_uint2(pk2(acc[K2 * 2 + rh][ct][0], acc[K2 * 2 + rh][ct][1]),
                               pk2(acc[K2 * 2 + rh][ct][2], acc[K2 * 2 + rh][ct][3]));
        *(uint2*)(pt + vt2_b(ct * 16 + lr, rh * 16 + lg * 4)) = pkv;
      }
    vb[K2][0] = *(const bf16x8*)(pt + vt2_b(lr, lg * 8));
    vb[K2][1] = *(const bf16x8*)(pt + vt2_b(16 + lr, lg * 8));
  }

  const float* bht = bias_att + w * NP * NP;
  f32x4 oacc[4][2];
  #pragma unroll
  for (int qt = 0; qt < 4; ++qt)
    #pragma unroll
    for (int jt = 0; jt < 2; ++jt) {
      oacc[qt][jt][0] = 0; oacc[qt][jt][1] = 0; oacc[qt][jt][2] = 0; oacc[qt][jt][3] = 0;
    }
  #pragma unroll 2
  for (int qt = 0; qt < 4; ++qt) {
    f32x4 s[4];
    #pragma unroll
    for (int ct = 0; ct < 4; ++ct) {
      const float4 sbv = *(const float4*)(bht + (ct * 16 + lr) * NP + qt * 16 + lg * 4);
      f32x4 sb; sb[0] = sbv.x; sb[1] = sbv.y; sb[2] = sbv.z; sb[3] = sbv.w;
      s[ct] = __builtin_amdgcn_mfma_f32_16x16x32_bf16(qa[qt], kb[ct], sb, 0, 0, 0);
    }
    float mx[4], si[4];
    #pragma unroll
    for (int r = 0; r < 4; ++r) {
      float m = fmaxf(fmaxf(s[0][r], s[1][r]), fmaxf(s[2][r], s[3][r]));
      m = fmaxf(m, __shfl_xor(m, 1, 64));
      m = fmaxf(m, __shfl_xor(m, 2, 64));
      m = fmaxf(m, __shfl_xor(m, 4, 64));
      m = fmaxf(m, __shfl_xor(m, 8, 64));
      mx[r] = m;
    }
    #pragma unroll
    for (int ct = 0; ct < 4; ++ct)
      #pragma unroll
      for (int r = 0; r < 4; ++r)
        s[ct][r] = __expf(s[ct][r] - mx[r]);
    #pragma unroll
    for (int r = 0; r < 4; ++r) {
      float t = s[0][r] + s[1][r] + s[2][r] + s[3][r];
      t += __shfl_xor(t, 1, 64);
      t += __shfl_xor(t, 2, 64);
      t += __shfl_xor(t, 4, 64);
      t += __shfl_xor(t, 8, 64);
      si[r] = __builtin_amdgcn_rcpf(t);
    }
    #pragma unroll
    for (int ct = 0; ct < 4; ++ct)
      #pragma unroll
      for (int r = 0; r < 4; ++r)
        *(short*)(pt + p2_b(lg * 4 + r, ct * 16 + lr)) =
            (short)f2bf_u(s[ct][r] * si[r]);
    #pragma unroll
    for (int kk = 0; kk < 2; ++kk) {
      const bf16x8 pa = *(const bf16x8*)(pt + p2_b(lr, kk * 32 + lg * 8));
      #pragma unroll
      for (int jt = 0; jt < 2; ++jt)
        oacc[qt][jt] = __builtin_amdgcn_mfma_f32_16x16x32_bf16(pa, vb[kk][jt], oacc[qt][jt], 0, 0, 0);
    }
  }

  __syncthreads();
  #pragma unroll
  for (int qt = 0; qt < 4; ++qt)
    #pragma unroll
    for (int jt = 0; jt < 2; ++jt)
      #pragma unroll
      for (int r = 0; r < 4; ++r)
        *(short*)(sx1 + sx_b(qt * 16 + lg * 4 + r, w * 32 + jt * 16 + lr)) =
            (short)f2bf_u(oacc[qt][jt][r]);
  __syncthreads();

  gemm32c(sx1, wp, proj_b, acc, w * 32, lr, lg);
  float* og = out + (size_t)b * NTOK * CDIM;
  #pragma unroll
  for (int rt = 0; rt < 4; ++rt)
    #pragma unroll
    for (int r = 0; r < 4; ++r) {
      const int row = rt * 16 + lg * 4 + r;
      if (row < NTOK) {
        #pragma unroll
        for (int ct = 0; ct < 2; ++ct)
          og[row * CDIM + w * 32 + ct * 16 + lr] = acc[rt][ct][r];
      }
    }
}

extern "C" void kernel_launch(void* const* d_in, const int* in_sizes, int n_in,
                              void* d_out, int out_size, void* d_ws, size_t ws_size,
                              hipStream_t stream) {
  const float* x1     = (const float*)d_in[0];
  const float* x2     = (const float*)d_in[1];
  const float* qkv_w  = (const float*)d_in[2];
  const float* qkv_b  = (const float*)d_in[3];
  const float* proj_w = (const float*)d_in[4];
  const float* proj_b = (const float*)d_in[5];
  const float* rpb    = (const float*)d_in[6];
  const int*   rel    = (const int*)d_in[7];

  char* ws = (char*)d_ws;
  short* wqkv     = (short*)ws;                         // 393216 B
  short* wp       = (short*)(ws + 393216);              // 131072 B
  float* bias_s   = (float*)(ws + 524288);              // 3072 B
  float* bias_att = (float*)(ws + 527360);              // 131072 B (transposed [h][key][query])
  char*  img      = ws + 658432;                        // Bn * 96 KB tiled images

  const int prep_total = 768 * 256 + 256 * 256 + 768 + NH * NP * NP;
  prep_kernel<<<(prep_total + 255) / 256, 256, 0, stream>>>(
      qkv_w, qkv_b, proj_w, rpb, rel, wqkv, wp, bias_s, bias_att);

  const int Bn = in_sizes[0] / (NTOK * CDIM);
  const size_t need = 658432 + (size_t)Bn * IMG_STRIDE;

  if (ws_size >= need) {
    (void)hipFuncSetAttribute((const void*)qkv_kernel,
                              hipFuncAttributeMaxDynamicSharedMemorySize, 81920);
    (void)hipFuncSetAttribute((const void*)attnproj_kernel,
                              hipFuncAttributeMaxDynamicSharedMemorySize, 40960);
    qkv_kernel<<<Bn, 512, 81920, stream>>>(x1, x2, wqkv, bias_s, img);
    attnproj_kernel<<<Bn, 256, 40960, stream>>>(img, wp, proj_b, bias_att, (float*)d_out);
  } else {
    const size_t shmem = 32768 + 32768 + 8 * 2048;      // 80 KB
    (void)hipFuncSetAttribute((const void*)fused3,
                              hipFuncAttributeMaxDynamicSharedMemorySize, (int)shmem);
    fused3<<<Bn, 512, shmem, stream>>>(x1, x2, wqkv, bias_s, wp, proj_b, bias_att,
                                       (float*)d_out);
  }
}

// Round 17
// 249.689 us; speedup vs baseline: 1.0212x; 1.0212x over previous
//
#include <hip/hip_runtime.h>
#include <hip/hip_bf16.h>

#define NTOK 49
#define NP 64
#define CDIM 256
#define NH 8
#define SCALE 0.17677669529663687f

// per-batch ws images, TILED (plain in global):
//   Q: 8 tiles [64 rows][32 cols] bf16 (4KB/head)  at +0
//   K: same                                        at +32768
//   Vt: 8 tiles [32 feat][64 tok] bf16             at +65536
#define IMG_STRIDE 98304

using f32x4  = __attribute__((ext_vector_type(4))) float;
using bf16x8 = __attribute__((ext_vector_type(8))) short;

__device__ __forceinline__ unsigned f2bf_u(float f) {
  union { float f; unsigned u; } c; c.f = f;
  return (c.u + 0x7fffu + ((c.u >> 16) & 1u)) >> 16;   // RNE
}
__device__ __forceinline__ unsigned pk2(float a, float b) {
  return f2bf_u(a) | (f2bf_u(b) << 16);
}

// ---- LDS byte-offset helpers (XOR swizzles preserve 16B alignment) ----
__device__ __forceinline__ int sx_b(int row, int col) {   // bf16 [64][256] x-stage / O image
  return (row * 512 + col * 2) ^ ((row & 7) << 4);
}
__device__ __forceinline__ int sp_b(int w, int row, int key) { // bf16 per-wave [16][64] P
  return w * 2048 + ((row * 128 + key * 2) ^ ((row & 7) << 4));
}
// wave-private 2KB patch: 32 logical rows x 64B, XOR bits 5-6 by (row>>2)&3
__device__ __forceinline__ int pt_b(int prow, int byte_in_row) {
  return (prow * 64 + byte_in_row) ^ (((prow >> 2) & 3) << 5);
}
// fused3 fallback helpers
__device__ __forceinline__ int rm2_b(int row, int col) {  // [32][32] bf16 2KB
  return (row * 64 + col * 2) ^ ((row & 7) << 4);
}
__device__ __forceinline__ int vt2_b(int feat, int tok) { // [32][32] bf16 2KB
  return (feat * 64 + tok * 2) ^ ((feat & 7) << 4);
}
__device__ __forceinline__ int p2_b(int q, int tok) {     // [16][64] bf16 2KB
  return (q * 128 + tok * 2) ^ ((q & 7) << 4);
}

// ---------------- prep: bf16 weights (scale folded into Wq), TRANSPOSED bias table
// bias_att layout: [h][key_col][query_row] f32
__global__ void prep_kernel(const float* __restrict__ qkv_w, const float* __restrict__ qkv_b,
                            const float* __restrict__ proj_w,
                            const float* __restrict__ rpb, const int* __restrict__ rel,
                            short* __restrict__ wqkv, short* __restrict__ wp,
                            float* __restrict__ bias_s, float* __restrict__ bias_att) {
  int i = blockIdx.x * 256 + threadIdx.x;
  if (i < 768 * 256) {
    int j = i >> 8;
    float v = qkv_w[i] * (j < 256 ? SCALE : 1.0f);
    wqkv[i] = (short)f2bf_u(v);
    return;
  }
  i -= 768 * 256;
  if (i < 256 * 256) { wp[i] = (short)f2bf_u(proj_w[i]); return; }
  i -= 256 * 256;
  if (i < 768) { bias_s[i] = qkv_b[i] * (i < 256 ? SCALE : 1.0f); return; }
  i -= 768;
  if (i < NH * NP * NP) {
    int h = i >> 12, rem = i & 4095, c = rem >> 6, r = rem & 63;
    float v;
    if (c >= NTOK)      v = -1e30f;      // mask padded key columns
    else if (r >= NTOK) v = 0.0f;        // padded query rows
    else                v = rpb[rel[r * NTOK + c] * NH + h];
    bias_att[i] = v;
  }
}

// 64x32(x256) per-wave GEMM, k-outer (used by producer, consumer proj, fallback)
__device__ __forceinline__ void gemm32c(const char* sxc, const short* __restrict__ wg,
                                        const float* __restrict__ bias,
                                        f32x4 acc[4][2], int col0, int lr, int lg) {
  const short* wr0 = wg + (col0 + lr) * CDIM + lg * 8;
  const short* wr1 = wg + (col0 + 16 + lr) * CDIM + lg * 8;
  const float bv0 = bias[col0 + lr];
  const float bv1 = bias[col0 + 16 + lr];
  #pragma unroll
  for (int rt = 0; rt < 4; ++rt) {
    #pragma unroll
    for (int r = 0; r < 4; ++r) { acc[rt][0][r] = bv0; acc[rt][1][r] = bv1; }
  }
  #pragma unroll
  for (int k = 0; k < 8; ++k) {
    const bf16x8 b0 = *(const bf16x8*)(wr0 + k * 32);
    const bf16x8 b1 = *(const bf16x8*)(wr1 + k * 32);
    #pragma unroll
    for (int rt = 0; rt < 4; ++rt) {
      const bf16x8 af = *(const bf16x8*)(sxc + sx_b(rt * 16 + lr, k * 32 + lg * 8));
      acc[rt][0] = __builtin_amdgcn_mfma_f32_16x16x32_bf16(af, b0, acc[rt][0], 0, 0, 0);
      acc[rt][1] = __builtin_amdgcn_mfma_f32_16x16x32_bf16(af, b1, acc[rt][1], 0, 0, 0);
    }
  }
}

// stage one batch of x (f32->bf16, rows >=49 zeroed); 512 threads.
// BATCHED: all 8 float4 loads issued, sched_barrier(0) fence, then convert+store.
// Forces 8 outstanding HBM loads per thread (2 latency windows total vs ~8).
__device__ __forceinline__ void stage_x_batched(char* sxc, const float* __restrict__ xg,
                                                int tid) {
  float4 v[8];
  #pragma unroll
  for (int it = 0; it < 8; ++it) {
    const int i = tid + it * 512;
    const int row = i >> 6, c4 = i & 63;
    if (row < NTOK) v[it] = *(const float4*)(xg + row * CDIM + c4 * 4);
    else            v[it] = make_float4(0.f, 0.f, 0.f, 0.f);
  }
  __builtin_amdgcn_sched_barrier(0);   // pin: all loads issued before any convert/store
  #pragma unroll
  for (int it = 0; it < 8; ++it) {
    const int i = tid + it * 512;
    const int row = i >> 6, c4 = i & 63;
    uint2 pkv = make_uint2(pk2(v[it].x, v[it].y), pk2(v[it].z, v[it].w));
    *(uint2*)(sxc + sx_b(row, c4 * 4)) = pkv;
  }
}

// plain stage (fallback kernel)
__device__ __forceinline__ void stage_x(char* sxc, const float* __restrict__ xg, int tid) {
  #pragma unroll
  for (int it = 0; it < 8; ++it) {
    const int i = tid + it * 512;
    const int row = i >> 6, c4 = i & 63;
    uint2 pkv = make_uint2(0u, 0u);
    if (row < NTOK) {
      const float4 v = *(const float4*)(xg + row * CDIM + c4 * 4);
      pkv.x = pk2(v.x, v.y); pkv.y = pk2(v.z, v.w);
    }
    *(uint2*)(sxc + sx_b(row, c4 * 4)) = pkv;
  }
}

// acc (64 rows x 32 cols) -> row-major tile [64][32] bf16 via 2KB wave patch.
__device__ __forceinline__ void store_rm_tile(char* __restrict__ gt, const f32x4 acc[4][2],
                                              char* pt, int lane, int lr, int lg) {
  #pragma unroll 1
  for (int R = 0; R < 2; ++R) {
    #pragma unroll
    for (int rh = 0; rh < 2; ++rh)
      #pragma unroll
      for (int ct = 0; ct < 2; ++ct)
        #pragma unroll
        for (int r = 0; r < 4; ++r) {
          const int prow = rh * 16 + lg * 4 + r;
          *(short*)(pt + pt_b(prow, (ct * 16 + lr) * 2)) =
              (short)f2bf_u(acc[2 * R + rh][ct][r]);
        }
    #pragma unroll
    for (int i = 0; i < 2; ++i) {
      const int c = i * 64 + lane;
      const int prow = c >> 2, seg = c & 3;
      const float4 v = *(const float4*)(pt + pt_b(prow, seg * 16));
      *(float4*)(gt + (R * 32 + prow) * 64 + seg * 16) = v;
    }
  }
}

// acc (rows=tok, cols=feat) -> Vt tile [32 feat][64 tok] bf16 via patch.
__device__ __forceinline__ void store_vt_tile(char* __restrict__ gt, const f32x4 acc[4][2],
                                              char* pt, int lane, int lr, int lg) {
  #pragma unroll 1
  for (int R = 0; R < 2; ++R) {
    #pragma unroll
    for (int rh = 0; rh < 2; ++rh)
      #pragma unroll
      for (int ct = 0; ct < 2; ++ct) {
        const int f = ct * 16 + lr;
        const int tok = rh * 16 + lg * 4;
        uint2 pkv = make_uint2(pk2(acc[2 * R + rh][ct][0], acc[2 * R + rh][ct][1]),
                               pk2(acc[2 * R + rh][ct][2], acc[2 * R + rh][ct][3]));
        *(uint2*)(pt + pt_b(f, tok * 2)) = pkv;
      }
    #pragma unroll
    for (int i = 0; i < 2; ++i) {
      const int c = i * 64 + lane;
      const int f = c >> 2, seg = c & 3;
      const float4 v = *(const float4*)(pt + pt_b(f, seg * 16));
      *(float4*)(gt + f * 128 + R * 64 + seg * 16) = v;
    }
  }
}

// ================= producer (R8 structure + batched staging) =================
__global__ __launch_bounds__(512, 2)
void qkv_kernel(const float* __restrict__ x1, const float* __restrict__ x2,
                const short* __restrict__ wqkv, const float* __restrict__ bias_s,
                char* __restrict__ img) {
  extern __shared__ char ldsq[];
  char* sx1   = ldsq;                 // 32 KB x1
  char* sx2   = ldsq + 32768;         // 32 KB x2
  char* patch = ldsq + 65536;         // 8 x 2 KB wave patches

  const int tid = threadIdx.x;
  const int w = tid >> 6, lane = tid & 63;
  const int lr = lane & 15, lg = lane >> 4;
  const int b = blockIdx.x;
  char* wsb = img + (size_t)b * IMG_STRIDE;
  char* pt = patch + w * 2048;
  const int ht = w;                    // wave = head slice

  stage_x_batched(sx1, x1 + (size_t)b * NTOK * CDIM, tid);
  stage_x_batched(sx2, x2 + (size_t)b * NTOK * CDIM, tid);
  __syncthreads();

  f32x4 acc[4][2];

  gemm32c(sx1, wqkv, bias_s, acc, ht * 32, lr, lg);
  store_rm_tile(wsb + ht * 4096, acc, pt, lane, lr, lg);

  gemm32c(sx2, wqkv + 512 * CDIM, bias_s + 512, acc, ht * 32, lr, lg);
  store_vt_tile(wsb + 65536 + ht * 4096, acc, pt, lane, lr, lg);

  gemm32c(sx2, wqkv + 256 * CDIM, bias_s + 256, acc, ht * 32, lr, lg);
  store_rm_tile(wsb + 32768 + ht * 4096, acc, pt, lane, lr, lg);
}

// ================= consumer (R11/R15 verbatim -- ~75 us) =================
__global__ __launch_bounds__(256, 2)
void attnproj_kernel(const char* __restrict__ img, const short* __restrict__ wp,
                     const float* __restrict__ proj_b, const float* __restrict__ bias_att,
                     float* __restrict__ out) {
  extern __shared__ char ldsc[];
  char* soc = ldsc;            // 32 KB O image (sx_b LDS layout)
  char* spc = ldsc + 32768;    // 8 KB P (2 KB per wave)

  const int tid = threadIdx.x;
  const int w = tid >> 6, lane = tid & 63;
  const int lr = lane & 15, lg = lane >> 4;
  const int b = blockIdx.x;
  const char* qimg = img + (size_t)b * IMG_STRIDE;
  const char* kimg = qimg + 32768;
  const char* vimg = qimg + 65536;

  #pragma unroll 1
  for (int hh = 0; hh < 2; ++hh) {
    const int h = w * 2 + hh;
    bf16x8 kb[4];
    #pragma unroll
    for (int ct = 0; ct < 4; ++ct)
      kb[ct] = *(const bf16x8*)(kimg + h * 4096 + (ct * 16 + lr) * 64 + lg * 16);
    bf16x8 vb[2][2];
    #pragma unroll
    for (int kk = 0; kk < 2; ++kk)
      #pragma unroll
      for (int jt = 0; jt < 2; ++jt)
        vb[kk][jt] = *(const bf16x8*)(vimg + h * 4096 + (jt * 16 + lr) * 128 + kk * 64 + lg * 16);
    const float* bht = bias_att + h * NP * NP;   // [key][query]

    #pragma unroll 2
    for (int qt = 0; qt < 4; ++qt) {
      const bf16x8 qa = *(const bf16x8*)(qimg + h * 4096 + (qt * 16 + lr) * 64 + lg * 16);
      f32x4 s[4];
      #pragma unroll
      for (int ct = 0; ct < 4; ++ct) {
        const float4 sbv = *(const float4*)(bht + (ct * 16 + lr) * NP + qt * 16 + lg * 4);
        f32x4 sb; sb[0] = sbv.x; sb[1] = sbv.y; sb[2] = sbv.z; sb[3] = sbv.w;
        s[ct] = __builtin_amdgcn_mfma_f32_16x16x32_bf16(qa, kb[ct], sb, 0, 0, 0);
      }
      float mx[4], si[4];
      #pragma unroll
      for (int r = 0; r < 4; ++r) {
        float m = fmaxf(fmaxf(s[0][r], s[1][r]), fmaxf(s[2][r], s[3][r]));
        m = fmaxf(m, __shfl_xor(m, 1, 64));
        m = fmaxf(m, __shfl_xor(m, 2, 64));
        m = fmaxf(m, __shfl_xor(m, 4, 64));
        m = fmaxf(m, __shfl_xor(m, 8, 64));
        mx[r] = m;
      }
      #pragma unroll
      for (int ct = 0; ct < 4; ++ct)
        #pragma unroll
        for (int r = 0; r < 4; ++r)
          s[ct][r] = __expf(s[ct][r] - mx[r]);
      #pragma unroll
      for (int r = 0; r < 4; ++r) {
        float t = s[0][r] + s[1][r] + s[2][r] + s[3][r];
        t += __shfl_xor(t, 1, 64);
        t += __shfl_xor(t, 2, 64);
        t += __shfl_xor(t, 4, 64);
        t += __shfl_xor(t, 8, 64);
        si[r] = __builtin_amdgcn_rcpf(t);
      }
      #pragma unroll
      for (int ct = 0; ct < 4; ++ct)
        #pragma unroll
        for (int r = 0; r < 4; ++r)
          *(short*)(spc + sp_b(w, lg * 4 + r, ct * 16 + lr)) =
              (short)f2bf_u(s[ct][r] * si[r]);
      f32x4 oq[2];
      #pragma unroll
      for (int jt = 0; jt < 2; ++jt) { oq[jt][0] = 0; oq[jt][1] = 0; oq[jt][2] = 0; oq[jt][3] = 0; }
      #pragma unroll
      for (int kk = 0; kk < 2; ++kk) {
        const bf16x8 pa = *(const bf16x8*)(spc + sp_b(w, lr, kk * 32 + lg * 8));
        #pragma unroll
        for (int jt = 0; jt < 2; ++jt)
          oq[jt] = __builtin_amdgcn_mfma_f32_16x16x32_bf16(pa, vb[kk][jt], oq[jt], 0, 0, 0);
      }
      #pragma unroll
      for (int jt = 0; jt < 2; ++jt)
        #pragma unroll
        for (int r = 0; r < 4; ++r)
          *(short*)(soc + sx_b(qt * 16 + lg * 4 + r, h * 32 + jt * 16 + lr)) =
              (short)f2bf_u(oq[jt][r]);
    }
  }
  __syncthreads();   // O image complete

  float* og = out + (size_t)b * NTOK * CDIM;
  #pragma unroll 1
  for (int p = 0; p < 2; ++p) {
    const int c0 = w * 64 + p * 32;
    const short* wr0 = wp + (c0 + lr) * CDIM + lg * 8;
    const short* wr1 = wp + (c0 + 16 + lr) * CDIM + lg * 8;
    const float bv0 = proj_b[c0 + lr];
    const float bv1 = proj_b[c0 + 16 + lr];
    f32x4 acc[4][2];
    #pragma unroll
    for (int rt = 0; rt < 4; ++rt)
      #pragma unroll
      for (int r = 0; r < 4; ++r) { acc[rt][0][r] = bv0; acc[rt][1][r] = bv1; }
    #pragma unroll
    for (int k = 0; k < 8; ++k) {
      const bf16x8 b0 = *(const bf16x8*)(wr0 + k * 32);
      const bf16x8 b1 = *(const bf16x8*)(wr1 + k * 32);
      #pragma unroll
      for (int rt = 0; rt < 4; ++rt) {
        const bf16x8 af = *(const bf16x8*)(soc + sx_b(rt * 16 + lr, k * 32 + lg * 8));
        acc[rt][0] = __builtin_amdgcn_mfma_f32_16x16x32_bf16(af, b0, acc[rt][0], 0, 0, 0);
        acc[rt][1] = __builtin_amdgcn_mfma_f32_16x16x32_bf16(af, b1, acc[rt][1], 0, 0, 0);
      }
    }
    #pragma unroll
    for (int rt = 0; rt < 4; ++rt)
      #pragma unroll
      for (int r = 0; r < 4; ++r) {
        const int row = rt * 16 + lg * 4 + r;
        if (row < NTOK) {
          #pragma unroll
          for (int ct = 0; ct < 2; ++ct)
            og[row * CDIM + c0 + ct * 16 + lr] = acc[rt][ct][r];
        }
      }
  }
}

// ================= FUSED FALLBACK (R12 fused3, verified) =================
__global__ __launch_bounds__(512, 2)
void fused3(const float* __restrict__ x1, const float* __restrict__ x2,
            const short* __restrict__ wqkv, const float* __restrict__ bias_s,
            const short* __restrict__ wp, const float* __restrict__ proj_b,
            const float* __restrict__ bias_att, float* __restrict__ out) {
  extern __shared__ char lds[];
  char* sx1 = lds;
  char* sx2 = lds + 32768;
  char* pat = lds + 65536;

  const int tid = threadIdx.x;
  const int w = tid >> 6, lane = tid & 63;
  const int lr = lane & 15, lg = lane >> 4;
  const int b = blockIdx.x;
  char* pt = pat + w * 2048;

  stage_x(sx1, x1 + (size_t)b * NTOK * CDIM, tid);
  stage_x(sx2, x2 + (size_t)b * NTOK * CDIM, tid);
  __syncthreads();

  f32x4 acc[4][2];
  bf16x8 qa[4];
  gemm32c(sx1, wqkv, bias_s, acc, w * 32, lr, lg);
  #pragma unroll
  for (int R = 0; R < 2; ++R) {
    #pragma unroll
    for (int rh = 0; rh < 2; ++rh)
      #pragma unroll
      for (int ct = 0; ct < 2; ++ct)
        #pragma unroll
        for (int r = 0; r < 4; ++r)
          *(short*)(pt + rm2_b(rh * 16 + lg * 4 + r, ct * 16 + lr)) =
              (short)f2bf_u(acc[R * 2 + rh][ct][r]);
    qa[R * 2 + 0] = *(const bf16x8*)(pt + rm2_b(lr, lg * 8));
    qa[R * 2 + 1] = *(const bf16x8*)(pt + rm2_b(16 + lr, lg * 8));
  }
  bf16x8 kb[4];
  gemm32c(sx2, wqkv + 256 * CDIM, bias_s + 256, acc, w * 32, lr, lg);
  #pragma unroll
  for (int R = 0; R < 2; ++R) {
    #pragma unroll
    for (int rh = 0; rh < 2; ++rh)
      #pragma unroll
      for (int ct = 0; ct < 2; ++ct)
        #pragma unroll
        for (int r = 0; r < 4; ++r)
          *(short*)(pt + rm2_b(rh * 16 + lg * 4 + r, ct * 16 + lr)) =
              (short)f2bf_u(acc[R * 2 + rh][ct][r]);
    kb[R * 2 + 0] = *(const bf16x8*)(pt + rm2_b(lr, lg * 8));
    kb[R * 2 + 1] = *(const bf16x8*)(pt + rm2_b(16 + lr, lg * 8));
  }
  bf16x8 vb[2][2];
  gemm32c(sx2, wqkv + 512 * CDIM, bias_s + 512, acc, w * 32, lr, lg);
  #pragma unroll
  for (int K2 = 0; K2 < 2; ++K2) {
    #pragma unroll
    for (int rh = 0; rh < 2; ++rh)
      #pragma unroll
      for (int ct = 0; ct < 2; ++ct) {
        uint2 pkv = make_uint2(pk2(acc[K2 * 2 + rh][ct][0], acc[K2 * 2 + rh][ct][1]),
                               pk2(acc[K2 * 2 + rh][ct][2], acc[K2 * 2 + rh][ct][3]));
        *(uint2*)(pt + vt2_b(ct * 16 + lr, rh * 16 + lg * 4)) = pkv;
      }
    vb[K2][0] = *(const bf16x8*)(pt + vt2_b(lr, lg * 8));
    vb[K2][1] = *(const bf16x8*)(pt + vt2_b(16 + lr, lg * 8));
  }

  const float* bht = bias_att + w * NP * NP;
  f32x4 oacc[4][2];
  #pragma unroll
  for (int qt = 0; qt < 4; ++qt)
    #pragma unroll
    for (int jt = 0; jt < 2; ++jt) {
      oacc[qt][jt][0] = 0; oacc[qt][jt][1] = 0; oacc[qt][jt][2] = 0; oacc[qt][jt][3] = 0;
    }
  #pragma unroll 2
  for (int qt = 0; qt < 4; ++qt) {
    f32x4 s[4];
    #pragma unroll
    for (int ct = 0; ct < 4; ++ct) {
      const float4 sbv = *(const float4*)(bht + (ct * 16 + lr) * NP + qt * 16 + lg * 4);
      f32x4 sb; sb[0] = sbv.x; sb[1] = sbv.y; sb[2] = sbv.z; sb[3] = sbv.w;
      s[ct] = __builtin_amdgcn_mfma_f32_16x16x32_bf16(qa[qt], kb[ct], sb, 0, 0, 0);
    }
    float mx[4], si[4];
    #pragma unroll
    for (int r = 0; r < 4; ++r) {
      float m = fmaxf(fmaxf(s[0][r], s[1][r]), fmaxf(s[2][r], s[3][r]));
      m = fmaxf(m, __shfl_xor(m, 1, 64));
      m = fmaxf(m, __shfl_xor(m, 2, 64));
      m = fmaxf(m, __shfl_xor(m, 4, 64));
      m = fmaxf(m, __shfl_xor(m, 8, 64));
      mx[r] = m;
    }
    #pragma unroll
    for (int ct = 0; ct < 4; ++ct)
      #pragma unroll
      for (int r = 0; r < 4; ++r)
        s[ct][r] = __expf(s[ct][r] - mx[r]);
    #pragma unroll
    for (int r = 0; r < 4; ++r) {
      float t = s[0][r] + s[1][r] + s[2][r] + s[3][r];
      t += __shfl_xor(t, 1, 64);
      t += __shfl_xor(t, 2, 64);
      t += __shfl_xor(t, 4, 64);
      t += __shfl_xor(t, 8, 64);
      si[r] = __builtin_amdgcn_rcpf(t);
    }
    #pragma unroll
    for (int ct = 0; ct < 4; ++ct)
      #pragma unroll
      for (int r = 0; r < 4; ++r)
        *(short*)(pt + p2_b(lg * 4 + r, ct * 16 + lr)) =
            (short)f2bf_u(s[ct][r] * si[r]);
    #pragma unroll
    for (int kk = 0; kk < 2; ++kk) {
      const bf16x8 pa = *(const bf16x8*)(pt + p2_b(lr, kk * 32 + lg * 8));
      #pragma unroll
      for (int jt = 0; jt < 2; ++jt)
        oacc[qt][jt] = __builtin_amdgcn_mfma_f32_16x16x32_bf16(pa, vb[kk][jt], oacc[qt][jt], 0, 0, 0);
    }
  }

  __syncthreads();
  #pragma unroll
  for (int qt = 0; qt < 4; ++qt)
    #pragma unroll
    for (int jt = 0; jt < 2; ++jt)
      #pragma unroll
      for (int r = 0; r < 4; ++r)
        *(short*)(sx1 + sx_b(qt * 16 + lg * 4 + r, w * 32 + jt * 16 + lr)) =
            (short)f2bf_u(oacc[qt][jt][r]);
  __syncthreads();

  gemm32c(sx1, wp, proj_b, acc, w * 32, lr, lg);
  float* og = out + (size_t)b * NTOK * CDIM;
  #pragma unroll
  for (int rt = 0; rt < 4; ++rt)
    #pragma unroll
    for (int r = 0; r < 4; ++r) {
      const int row = rt * 16 + lg * 4 + r;
      if (row < NTOK) {
        #pragma unroll
        for (int ct = 0; ct < 2; ++ct)
          og[row * CDIM + w * 32 + ct * 16 + lr] = acc[rt][ct][r];
      }
    }
}

extern "C" void kernel_launch(void* const* d_in, const int* in_sizes, int n_in,
                              void* d_out, int out_size, void* d_ws, size_t ws_size,
                              hipStream_t stream) {
  const float* x1     = (const float*)d_in[0];
  const float* x2     = (const float*)d_in[1];
  const float* qkv_w  = (const float*)d_in[2];
  const float* qkv_b  = (const float*)d_in[3];
  const float* proj_w = (const float*)d_in[4];
  const float* proj_b = (const float*)d_in[5];
  const float* rpb    = (const float*)d_in[6];
  const int*   rel    = (const int*)d_in[7];

  char* ws = (char*)d_ws;
  short* wqkv     = (short*)ws;                         // 393216 B
  short* wp       = (short*)(ws + 393216);              // 131072 B
  float* bias_s   = (float*)(ws + 524288);              // 3072 B
  float* bias_att = (float*)(ws + 527360);              // 131072 B (transposed [h][key][query])
  char*  img      = ws + 658432;                        // Bn * 96 KB tiled images

  const int prep_total = 768 * 256 + 256 * 256 + 768 + NH * NP * NP;
  prep_kernel<<<(prep_total + 255) / 256, 256, 0, stream>>>(
      qkv_w, qkv_b, proj_w, rpb, rel, wqkv, wp, bias_s, bias_att);

  const int Bn = in_sizes[0] / (NTOK * CDIM);
  const size_t need = 658432 + (size_t)Bn * IMG_STRIDE;

  if (ws_size >= need) {
    (void)hipFuncSetAttribute((const void*)qkv_kernel,
                              hipFuncAttributeMaxDynamicSharedMemorySize, 81920);
    (void)hipFuncSetAttribute((const void*)attnproj_kernel,
                              hipFuncAttributeMaxDynamicSharedMemorySize, 40960);
    qkv_kernel<<<Bn, 512, 81920, stream>>>(x1, x2, wqkv, bias_s, img);
    attnproj_kernel<<<Bn, 256, 40960, stream>>>(img, wp, proj_b, bias_att, (float*)d_out);
  } else {
    const size_t shmem = 32768 + 32768 + 8 * 2048;      // 80 KB
    (void)hipFuncSetAttribute((const void*)fused3,
                              hipFuncAttributeMaxDynamicSharedMemorySize, (int)shmem);
    fused3<<<Bn, 512, shmem, stream>>>(x1, x2, wqkv, bias_s, wp, proj_b, bias_att,
                                       (float*)d_out);
  }
}